// Round 13
// baseline (292.010 us; speedup 1.0000x reference)
//
#include <hip/hip_runtime.h>
#include <hip/hip_bf16.h>
#include <math.h>

#define BATCH 65536
#define NODES 1024
#define ZD    256
#define KSA   512   // A split-K: [hi|lo] (hi reused for ksteps 4-7)
#define KSB   768   // B split-K: [hi|lo|hi]
#define EPSGAP 1.5e-3f
#define RB    8     // refine rows per block batch

// d_out layout (floats): z_e, k, z_q, nw, dist
#define OFF_ZE   0ull
#define OFF_K    16777216ull
#define OFF_ZQ   16842752ull
#define OFF_NW   33619968ull
#define OFF_DIST 100728832ull

typedef __attribute__((ext_vector_type(8))) short short8v;
typedef __attribute__((ext_vector_type(4))) float f32x4;

#define GLOAD16(g, l) __builtin_amdgcn_global_load_lds( \
    (const __attribute__((address_space(1))) void*)(g), \
    (__attribute__((address_space(3))) void*)(l), 16, 0, 0)

__device__ inline float wave_reduce_add(float s) {
#pragma unroll
    for (int off = 32; off; off >>= 1) s += __shfl_down(s, off);
    return s;
}

// non-temporal float4 store via clang ext_vector (HIP_vector_type not accepted)
__device__ inline void nt_store4(float* p, float4 v) {
    f32x4 t = {v.x, v.y, v.z, v.w};
    __builtin_nontemporal_store(t, (f32x4*)p);
}

// ---------------- split f32 -> (hi,lo) bf16 segments + row norms (+opt copy/zero) ----------------
__global__ __launch_bounds__(256) void split_k(const float* __restrict__ X,
                                               ushort* __restrict__ P,
                                               float* __restrict__ norms,
                                               float* __restrict__ copy_out,
                                               int* __restrict__ zero_cnt,
                                               int isA) {
    if (zero_cnt && blockIdx.x == 0 && threadIdx.x == 0) *zero_cnt = 0;
    int row  = blockIdx.x * 4 + (threadIdx.x >> 6);
    int lane = threadIdx.x & 63;
    float4 v = ((const float4*)(X + (size_t)row * ZD))[lane];
    if (copy_out) nt_store4(copy_out + (size_t)row * ZD + lane * 4, v);
    float s = v.x * v.x + v.y * v.y + v.z * v.z + v.w * v.w;
    s = wave_reduce_add(s);
    if (lane == 0) norms[row] = s;

    float xs[4] = {v.x, v.y, v.z, v.w};
    ushort hi[4], lo[4];
#pragma unroll
    for (int i = 0; i < 4; ++i) {
        __hip_bfloat16 h = __float2bfloat16(xs[i]);
        float hf = __bfloat162float(h);
        __hip_bfloat16 l = __float2bfloat16(xs[i] - hf);
        hi[i] = *(ushort*)&h;
        lo[i] = *(ushort*)&l;
    }
    ushort4 h4 = make_ushort4(hi[0], hi[1], hi[2], hi[3]);
    ushort4 l4 = make_ushort4(lo[0], lo[1], lo[2], lo[3]);
    if (isA) {
        ushort* base = P + (size_t)row * KSA + lane * 4;
        *(ushort4*)(base)       = h4;
        *(ushort4*)(base + 256) = l4;
    } else {
        ushort* base = P + (size_t)row * KSB + lane * 4;
        *(ushort4*)(base)       = h4;
        *(ushort4*)(base + 256) = l4;
        *(ushort4*)(base + 512) = h4;
    }
}

// ---------------- MFMA dist GEMM + fused per-block top-2 ----------------
// 128x128 tile, BK=64, DOUBLE-buffer 64KB LDS, counted vmcnt(8) + raw s_barrier
// (T4 minimum: prefetch loads stay in flight across barriers, no vmcnt(0) drain).
// SWAPPED operands: mfma(bf, af) -> acc[fn][fm][j] = D[M][N=wc*64+fn*16+fk*4+j]
__global__ __launch_bounds__(256, 2) void dist_mfma_k(const ushort* __restrict__ Ap,
                                                      const ushort* __restrict__ Bp,
                                                      const float* __restrict__ xn,
                                                      const float* __restrict__ yn,
                                                      float* __restrict__ D,
                                                      float4* __restrict__ partials) {
    __shared__ ushort As[2][128 * 64];   // 32KB
    __shared__ ushort Bs[2][128 * 64];   // 32KB

    const int tid  = threadIdx.x;
    const int lane = tid & 63;
    const int wave = tid >> 6;
    const int wr = wave >> 1, wc = wave & 1;

    int orig = blockIdx.x;
    int wg = (orig & 7) * 512 + (orig >> 3);   // 4096 % 8 == 0 -> bijective XCD swizzle
    const int bm = wg >> 3, bn = wg & 7;       // bn fastest within XCD -> A-panel L2 reuse

    f32x4 acc[4][4];   // [fn][fm]
#pragma unroll
    for (int i = 0; i < 4; ++i)
#pragma unroll
        for (int j = 0; j < 4; ++j) acc[i][j] = f32x4{0.f, 0.f, 0.f, 0.f};

    const int sg    = tid & 7;
    const int srow0 = tid >> 3;

    auto stage = [&](int buf, int kstep) {
        int a_koff = ((kstep < 4) ? kstep : (kstep - 4)) * 64;  // hi reused for 4-7
#pragma unroll
        for (int i = 0; i < 4; ++i) {
            int row = i * 32 + srow0;
            int ss = sg ^ (row & 7);
            const ushort* ga = Ap + (size_t)(bm * 128 + row) * KSA + a_koff + ss * 8;
            GLOAD16(ga, &As[buf][(row * 8 + sg) * 8]);
            const ushort* gb = Bp + (size_t)(bn * 128 + row) * KSB + kstep * 64 + ss * 8;
            GLOAD16(gb, &Bs[buf][(row * 8 + sg) * 8]);
        }
    };

    const int frow = lane & 15;
    const int fk   = lane >> 4;
    int a_off[4], a_x7[4], b_off[4], b_x7[4];
#pragma unroll
    for (int f = 0; f < 4; ++f) {
        int ar = wr * 64 + f * 16 + frow;
        a_off[f] = ar * 64;  a_x7[f] = ar & 7;
        int br = wc * 64 + f * 16 + frow;
        b_off[f] = br * 64;  b_x7[f] = br & 7;
    }

    auto compute = [&](int buf) {
#pragma unroll
        for (int k32 = 0; k32 < 2; ++k32) {
            int skb = k32 * 4 + fk;
            short8v af[4], bf[4];
#pragma unroll
            for (int f = 0; f < 4; ++f)
                af[f] = *(const short8v*)&As[buf][a_off[f] + ((skb ^ a_x7[f]) * 8)];
#pragma unroll
            for (int f = 0; f < 4; ++f)
                bf[f] = *(const short8v*)&Bs[buf][b_off[f] + ((skb ^ b_x7[f]) * 8)];
#pragma unroll
            for (int i = 0; i < 4; ++i)
#pragma unroll
                for (int j = 0; j < 4; ++j)
                    acc[i][j] = __builtin_amdgcn_mfma_f32_16x16x32_bf16(bf[i], af[j], acc[i][j], 0, 0, 0);
        }
    };

    // prologue
    stage(0, 0);
#pragma unroll
    for (int ks = 0; ks < 12; ++ks) {
        int cur = ks & 1;
        if (ks < 11) stage(cur ^ 1, ks + 1);         // 8 loads in flight across barriers
        if (ks < 11) asm volatile("s_waitcnt vmcnt(8)" ::: "memory");
        else         asm volatile("s_waitcnt vmcnt(0)" ::: "memory");
        __builtin_amdgcn_s_barrier();                 // all waves' tile-ks loads complete
        __builtin_amdgcn_sched_barrier(0);
        compute(cur);
        asm volatile("s_waitcnt lgkmcnt(0)" ::: "memory");
        __builtin_amdgcn_s_barrier();                 // all reads done before overwrite
    }

    // ---- epilogue: d = max(xn+yn-2*acc,0), coalesced NT float4 stores, top-2 ----
    const int n0 = bn * 128 + wc * 64 + fk * 4;     // + fn*16 : column base
    float4 ynv[4];
#pragma unroll
    for (int fn = 0; fn < 4; ++fn) ynv[fn] = *(const float4*)(yn + n0 + fn * 16);

    float4* red = (float4*)&As[0][0];   // As free after main loop; [128][2]

#pragma unroll
    for (int fm = 0; fm < 4; ++fm) {
        const int mloc = wr * 64 + fm * 16 + frow;  // local row in tile
        const size_t M = (size_t)(bm * 128 + mloc);
        float xv = xn[M];
        float* drow = D + M * NODES;
        float v1 = 3.4e38f, v2 = 3.4e38f;
        int   c1 = 1 << 30,  c2 = 1 << 30;
#pragma unroll
        for (int fn = 0; fn < 4; ++fn) {
            f32x4 a = acc[fn][fm];
            float4 d;
            d.x = fmaxf(xv + ynv[fn].x - 2.0f * a[0], 0.0f);
            d.y = fmaxf(xv + ynv[fn].y - 2.0f * a[1], 0.0f);
            d.z = fmaxf(xv + ynv[fn].z - 2.0f * a[2], 0.0f);
            d.w = fmaxf(xv + ynv[fn].w - 2.0f * a[3], 0.0f);
            nt_store4(drow + n0 + fn * 16, d);
            float dv[4] = {d.x, d.y, d.z, d.w};
#pragma unroll
            for (int j = 0; j < 4; ++j) {
                int c = n0 + fn * 16 + j;
                if (dv[j] < v1 || (dv[j] == v1 && c < c1)) { v2 = v1; c2 = c1; v1 = dv[j]; c1 = c; }
                else if (dv[j] < v2 || (dv[j] == v2 && c < c2)) { v2 = dv[j]; c2 = c; }
            }
        }
        // merge across the 4 fk lanes (same frow): xor offsets 16, 32
#pragma unroll
        for (int off = 16; off < 64; off <<= 1) {
            float w1 = __shfl_xor(v1, off); int d1 = __shfl_xor(c1, off);
            float w2 = __shfl_xor(v2, off); int d2 = __shfl_xor(c2, off);
            if (w1 < v1 || (w1 == v1 && d1 < c1)) { v2 = v1; c2 = c1; v1 = w1; c1 = d1; }
            else if (w1 < v2 || (w1 == v2 && d1 < c2)) { v2 = w1; c2 = d1; }
            if (w2 < v2 || (w2 == v2 && d2 < c2)) {
                if (w2 < v1 || (w2 == v1 && d2 < c1)) { v2 = v1; c2 = c1; v1 = w2; c1 = d2; }
                else { v2 = w2; c2 = d2; }
            }
        }
        if (fk == 0) red[mloc * 2 + wc] = make_float4(v1, (float)c1, v2, (float)c2);
    }
    __syncthreads();
    if (tid < 128) {
        float4 a = red[tid * 2 + 0];
        float4 b = red[tid * 2 + 1];
        float v1 = a.x, c1 = a.y, v2 = a.z, c2 = a.w;
        if (b.x < v1 || (b.x == v1 && b.y < c1)) { v2 = v1; c2 = c1; v1 = b.x; c1 = b.y; }
        else if (b.x < v2 || (b.x == v2 && b.y < c2)) { v2 = b.x; c2 = b.y; }
        if (b.z < v2 || (b.z == v2 && b.w < c2)) {
            if (b.z < v1 || (b.z == v1 && b.w < c1)) { v2 = v1; c2 = c1; v1 = b.z; c1 = b.w; }
            else { v2 = b.z; c2 = b.w; }
        }
        partials[(size_t)(bm * 128 + tid) * 8 + bn] = make_float4(v1, c1, v2, c2);
    }
}

// ---------------- merge 8 block top-2s -> k, list ambiguous rows ----------------
__global__ __launch_bounds__(256) void finish1_k(const float4* __restrict__ partials,
                                                 float* __restrict__ out_k,
                                                 int* __restrict__ refine_cnt,
                                                 int* __restrict__ refine_list) {
    int r = blockIdx.x * 256 + threadIdx.x;
    float v1 = 3.4e38f, c1 = 2.0e9f, v2 = 3.4e38f, c2 = 2.0e9f;
#pragma unroll
    for (int i = 0; i < 8; ++i) {
        float4 p = partials[(size_t)r * 8 + i];
        if (p.x < v1 || (p.x == v1 && p.y < c1)) { v2 = v1; c2 = c1; v1 = p.x; c1 = p.y; }
        else if (p.x < v2 || (p.x == v2 && p.y < c2)) { v2 = p.x; c2 = p.y; }
        if (p.z < v2 || (p.z == v2 && p.w < c2)) {
            if (p.z < v1 || (p.z == v1 && p.w < c1)) { v2 = v1; c2 = c1; v1 = p.z; c1 = p.w; }
            else { v2 = p.z; c2 = p.w; }
        }
    }
    out_k[r] = c1;
    if (v2 - v1 < EPSGAP) {
        int slot = atomicAdd(refine_cnt, 1);
        refine_list[slot] = r;
    }
}

// ---------------- exact f32 re-argmin for near-tie rows (8-row batches) ----------------
__global__ __launch_bounds__(256) void refine_k(const float* __restrict__ ze,
                                                const float* __restrict__ cb,
                                                const float* __restrict__ xn,
                                                const float* __restrict__ yn,
                                                const int* __restrict__ refine_cnt,
                                                const int* __restrict__ refine_list,
                                                float* __restrict__ out_k) {
    __shared__ float zs[RB][ZD];
    __shared__ float rvs[RB][4];
    __shared__ int   rcs[RB][4];
    const int n   = *refine_cnt;
    const int tid = threadIdx.x;
    const int lane = tid & 63, w = tid >> 6;

    for (int base = blockIdx.x * RB; base < n; base += gridDim.x * RB) {
        int nb = n - base; if (nb > RB) nb = RB;
        __syncthreads();
        {
            int rr = tid >> 5, p = tid & 31;
            if (rr < nb) {
                int r = refine_list[base + rr];
                const float4* zp = (const float4*)(ze + (size_t)r * ZD);
                ((float4*)zs[rr])[p]      = zp[p];
                ((float4*)zs[rr])[p + 32] = zp[p + 32];
            }
        }
        __syncthreads();

        float dot[RB][4];
#pragma unroll
        for (int rr = 0; rr < RB; ++rr)
#pragma unroll
            for (int m = 0; m < 4; ++m) dot[rr][m] = 0.0f;

        for (int k4 = 0; k4 < 64; ++k4) {
            float4 c[4];
#pragma unroll
            for (int m = 0; m < 4; ++m)
                c[m] = *(const float4*)(cb + (size_t)(tid + m * 256) * ZD + k4 * 4);
#pragma unroll
            for (int rr = 0; rr < RB; ++rr) {
                float4 zv = ((const float4*)zs[rr])[k4];
#pragma unroll
                for (int m = 0; m < 4; ++m) {
                    float d = dot[rr][m];
                    d = fmaf(zv.x, c[m].x, d);
                    d = fmaf(zv.y, c[m].y, d);
                    d = fmaf(zv.z, c[m].z, d);
                    d = fmaf(zv.w, c[m].w, d);
                    dot[rr][m] = d;
                }
            }
        }

        float ynv[4];
#pragma unroll
        for (int m = 0; m < 4; ++m) ynv[m] = yn[tid + m * 256];

        for (int rr = 0; rr < nb; ++rr) {
            int r = refine_list[base + rr];
            float xv = xn[r];
            float bv = 3.4e38f; int bc = 1 << 30;
#pragma unroll
            for (int m = 0; m < 4; ++m) {
                int j = tid + m * 256;
                float d = fmaxf((xv + ynv[m]) - 2.0f * dot[rr][m], 0.0f);
                if (d < bv) { bv = d; bc = j; }
            }
#pragma unroll
            for (int off = 32; off; off >>= 1) {
                float ov = __shfl_down(bv, off);
                int   oc = __shfl_down(bc, off);
                if (ov < bv || (ov == bv && oc < bc)) { bv = ov; bc = oc; }
            }
            if (lane == 0) { rvs[rr][w] = bv; rcs[rr][w] = bc; }
        }
        __syncthreads();
        if (tid < nb) {
            float fv = rvs[tid][0]; int fc = rcs[tid][0];
#pragma unroll
            for (int i = 1; i < 4; ++i)
                if (rvs[tid][i] < fv || (rvs[tid][i] == fv && rcs[tid][i] < fc)) { fv = rvs[tid][i]; fc = rcs[tid][i]; }
            out_k[refine_list[base + tid]] = (float)fc;
        }
    }
}

// ---------------- z_q gather + neighbour weights (separable Gaussian, nt stores) ----------------
__global__ __launch_bounds__(256) void finish2_k(const float* __restrict__ cb,
                                                 const int* __restrict__ epoch_p,
                                                 const float* __restrict__ kf,
                                                 float* __restrict__ out_zq,
                                                 float* __restrict__ out_nw) {
    __shared__ float g[32];   // g[t] = exp(-t^2/(2 sig^2)); w = g[|dx|]*g[|dy|]

    int ep = epoch_p[0];
    double sig = 16.0 * exp((double)ep * -0.034657359027997265);
    float ninv = (float)(-1.0 / (2.0 * sig * sig));
    if (threadIdx.x < 32) {
        float t = (float)threadIdx.x;
        g[threadIdx.x] = __expf(t * t * ninv);
    }
    __syncthreads();

    int row  = blockIdx.x * 4 + (threadIdx.x >> 6);
    int lane = threadIdx.x & 63;
    int k = (int)kf[row];

    nt_store4(out_zq + (size_t)row * ZD + lane * 4,
              ((const float4*)(cb + (size_t)k * ZD))[lane]);

    int kx = k >> 5, ky = k & 31;
    float* nwp = out_nw + (size_t)row * NODES;
#pragma unroll
    for (int i = 0; i < 4; ++i) {
        int q = i * 64 + lane;
        int n = q * 4;
        int nx = n >> 5;
        int ny = n & 31;
        float gx = g[abs(nx - ky)];
        float4 w;
        w.x = gx * g[abs(ny + 0 - kx)];
        w.y = gx * g[abs(ny + 1 - kx)];
        w.z = gx * g[abs(ny + 2 - kx)];
        w.w = gx * g[abs(ny + 3 - kx)];
        nt_store4(nwp + q * 4, w);
    }
}

extern "C" void kernel_launch(void* const* d_in, const int* in_sizes, int n_in,
                              void* d_out, int out_size, void* d_ws, size_t ws_size,
                              hipStream_t stream) {
    const float* z_e      = (const float*)d_in[0];
    const float* codebook = (const float*)d_in[1];
    const int*   epoch_p  = (const int*)d_in[2];
    float* out = (float*)d_out;

    // scratch in d_out regions overwritten later (stream-ordered):
    //  nw region (268MB): Ap, Bp, xn, yn, partials  (finish2 writes nw last)
    //  z_q region: refine count + list              (finish2 writes z_q last)
    char* scratch = (char*)(out + OFF_NW);
    ushort* Ap = (ushort*)scratch;                          // 67,108,864 B
    ushort* Bp = (ushort*)(scratch + 67108864);             //  1,572,864 B
    float*  xn = (float*) (scratch + 68681728);             //    262,144 B
    float*  yn = (float*) (scratch + 68943872);             //      4,096 B
    float4* partials = (float4*)(scratch + 68947968);       //  8,388,608 B
    int* refine_cnt  = (int*)(out + OFF_ZQ);
    int* refine_list = refine_cnt + 1;

    split_k<<<BATCH / 4, 256, 0, stream>>>(z_e, Ap, xn, out + OFF_ZE, nullptr, 1);
    split_k<<<NODES / 4, 256, 0, stream>>>(codebook, Bp, yn, nullptr, refine_cnt, 0);

    dist_mfma_k<<<4096, 256, 0, stream>>>(Ap, Bp, xn, yn, out + OFF_DIST, partials);

    finish1_k<<<BATCH / 256, 256, 0, stream>>>(partials, out + OFF_K, refine_cnt, refine_list);
    refine_k<<<512, 256, 0, stream>>>(z_e, codebook, xn, yn, refine_cnt, refine_list, out + OFF_K);
    finish2_k<<<BATCH / 4, 256, 0, stream>>>(codebook, epoch_p, out + OFF_K,
                                             out + OFF_ZQ, out + OFF_NW);
}

// Round 14
// 263.798 us; speedup vs baseline: 1.1069x; 1.1069x over previous
//
#include <hip/hip_runtime.h>
#include <hip/hip_bf16.h>
#include <math.h>

#define BATCH 65536
#define NODES 1024
#define ZD    256
#define KSA   512   // A split-K: [hi|lo] (hi staged once per chunk, reused for B.lo)
#define KSB   768   // B split-K: [hi|lo|hi]
#define EPSGAP 1.5e-3f
#define RB    8     // refine rows per block batch

// d_out layout (floats): z_e, k, z_q, nw, dist
#define OFF_ZE   0ull
#define OFF_K    16777216ull
#define OFF_ZQ   16842752ull
#define OFF_NW   33619968ull
#define OFF_DIST 100728832ull

typedef __attribute__((ext_vector_type(8))) short short8v;
typedef __attribute__((ext_vector_type(4))) float f32x4;

#define GLOAD16(g, l) __builtin_amdgcn_global_load_lds( \
    (const __attribute__((address_space(1))) void*)(g), \
    (__attribute__((address_space(3))) void*)(l), 16, 0, 0)

__device__ inline float wave_reduce_add(float s) {
#pragma unroll
    for (int off = 32; off; off >>= 1) s += __shfl_down(s, off);
    return s;
}

// non-temporal float4 store via clang ext_vector (HIP_vector_type not accepted)
__device__ inline void nt_store4(float* p, float4 v) {
    f32x4 t = {v.x, v.y, v.z, v.w};
    __builtin_nontemporal_store(t, (f32x4*)p);
}

// ---------------- split f32 -> (hi,lo) bf16 segments + row norms (+opt copy/zero) ----------------
__global__ __launch_bounds__(256) void split_k(const float* __restrict__ X,
                                               ushort* __restrict__ P,
                                               float* __restrict__ norms,
                                               float* __restrict__ copy_out,
                                               int* __restrict__ zero_cnt,
                                               int isA) {
    if (zero_cnt && blockIdx.x == 0 && threadIdx.x == 0) *zero_cnt = 0;
    int row  = blockIdx.x * 4 + (threadIdx.x >> 6);
    int lane = threadIdx.x & 63;
    float4 v = ((const float4*)(X + (size_t)row * ZD))[lane];
    if (copy_out) nt_store4(copy_out + (size_t)row * ZD + lane * 4, v);
    float s = v.x * v.x + v.y * v.y + v.z * v.z + v.w * v.w;
    s = wave_reduce_add(s);
    if (lane == 0) norms[row] = s;

    float xs[4] = {v.x, v.y, v.z, v.w};
    ushort hi[4], lo[4];
#pragma unroll
    for (int i = 0; i < 4; ++i) {
        __hip_bfloat16 h = __float2bfloat16(xs[i]);
        float hf = __bfloat162float(h);
        __hip_bfloat16 l = __float2bfloat16(xs[i] - hf);
        hi[i] = *(ushort*)&h;
        lo[i] = *(ushort*)&l;
    }
    ushort4 h4 = make_ushort4(hi[0], hi[1], hi[2], hi[3]);
    ushort4 l4 = make_ushort4(lo[0], lo[1], lo[2], lo[3]);
    if (isA) {
        ushort* base = P + (size_t)row * KSA + lane * 4;
        *(ushort4*)(base)       = h4;
        *(ushort4*)(base + 256) = l4;
    } else {
        ushort* base = P + (size_t)row * KSB + lane * 4;
        *(ushort4*)(base)       = h4;
        *(ushort4*)(base + 256) = l4;
        *(ushort4*)(base + 512) = h4;
    }
}

// ---------------- MFMA dist GEMM + fused per-block top-2 ----------------
// 128x128 tile, BK=64, single-buffer 32KB LDS, 4 blocks/CU (R12 proven config).
// K-schedule 0,4,1,5,2,6,3,7,8..11: A.hi chunk staged ONCE, consumed by B.hi
// then B.lo (B-only restage in between) -> per-thread loads 96 -> 80.
// SWAPPED operands: mfma(bf, af) -> acc[fn][fm][j] = D[M][N=wc*64+fn*16+fk*4+j]
__global__ __launch_bounds__(256, 4) void dist_mfma_k(const ushort* __restrict__ Ap,
                                                      const ushort* __restrict__ Bp,
                                                      const float* __restrict__ xn,
                                                      const float* __restrict__ yn,
                                                      float* __restrict__ D,
                                                      float4* __restrict__ partials) {
    __shared__ ushort As[128 * 64];   // 16KB
    __shared__ ushort Bs[128 * 64];   // 16KB

    const int tid  = threadIdx.x;
    const int lane = tid & 63;
    const int wave = tid >> 6;
    const int wr = wave >> 1, wc = wave & 1;

    int orig = blockIdx.x;
    int wg = (orig & 7) * 512 + (orig >> 3);   // 4096 % 8 == 0 -> bijective XCD swizzle
    const int bm = wg >> 3, bn = wg & 7;       // bn fastest within XCD -> A-panel L2 reuse

    f32x4 acc[4][4];   // [fn][fm]
#pragma unroll
    for (int i = 0; i < 4; ++i)
#pragma unroll
        for (int j = 0; j < 4; ++j) acc[i][j] = f32x4{0.f, 0.f, 0.f, 0.f};

    const int sg    = tid & 7;
    const int srow0 = tid >> 3;

    auto stage_a = [&](int a_koff) {
#pragma unroll
        for (int i = 0; i < 4; ++i) {
            int row = i * 32 + srow0;
            int ss = sg ^ (row & 7);
            const ushort* ga = Ap + (size_t)(bm * 128 + row) * KSA + a_koff + ss * 8;
            GLOAD16(ga, &As[(row * 8 + sg) * 8]);
        }
    };
    auto stage_b = [&](int kstep) {
#pragma unroll
        for (int i = 0; i < 4; ++i) {
            int row = i * 32 + srow0;
            int ss = sg ^ (row & 7);
            const ushort* gb = Bp + (size_t)(bn * 128 + row) * KSB + kstep * 64 + ss * 8;
            GLOAD16(gb, &Bs[(row * 8 + sg) * 8]);
        }
    };

    const int frow = lane & 15;
    const int fk   = lane >> 4;
    int a_off[4], a_x7[4], b_off[4], b_x7[4];
#pragma unroll
    for (int f = 0; f < 4; ++f) {
        int ar = wr * 64 + f * 16 + frow;
        a_off[f] = ar * 64;  a_x7[f] = ar & 7;
        int br = wc * 64 + f * 16 + frow;
        b_off[f] = br * 64;  b_x7[f] = br & 7;
    }

    auto compute = [&]() {
#pragma unroll
        for (int k32 = 0; k32 < 2; ++k32) {
            int skb = k32 * 4 + fk;
            short8v af[4], bf[4];
#pragma unroll
            for (int f = 0; f < 4; ++f)
                af[f] = *(const short8v*)&As[a_off[f] + ((skb ^ a_x7[f]) * 8)];
#pragma unroll
            for (int f = 0; f < 4; ++f)
                bf[f] = *(const short8v*)&Bs[b_off[f] + ((skb ^ b_x7[f]) * 8)];
#pragma unroll
            for (int i = 0; i < 4; ++i)
#pragma unroll
                for (int j = 0; j < 4; ++j)
                    acc[i][j] = __builtin_amdgcn_mfma_f32_16x16x32_bf16(bf[i], af[j], acc[i][j], 0, 0, 0);
        }
    };

    // K-schedule: (b_kstep, stage_a?) — A chunk c serves B.hi(c) then B.lo(c).
    const int  bks[12] = {0, 4, 1, 5, 2, 6, 3, 7, 8, 9, 10, 11};
    const bool sta[12] = {1, 0, 1, 0, 1, 0, 1, 0, 1, 1, 1, 1};
#pragma unroll
    for (int i = 0; i < 12; ++i) {
        int ks = bks[i];
        if (sta[i]) stage_a(((ks < 4) ? ks : (ks - 4)) * 64);
        stage_b(ks);
        __syncthreads();       // drains vmcnt -> LDS tile ready
        compute();
        __syncthreads();       // all reads done before next-overwrite
    }

    // ---- epilogue: d = max(xn+yn-2*acc,0), coalesced NT float4 stores, top-2 ----
    const int n0 = bn * 128 + wc * 64 + fk * 4;     // + fn*16 : column base
    float4 ynv[4];
#pragma unroll
    for (int fn = 0; fn < 4; ++fn) ynv[fn] = *(const float4*)(yn + n0 + fn * 16);

    float4* red = (float4*)&As[0];   // As free after main loop; [128][2]

#pragma unroll
    for (int fm = 0; fm < 4; ++fm) {
        const int mloc = wr * 64 + fm * 16 + frow;  // local row in tile
        const size_t M = (size_t)(bm * 128 + mloc);
        float xv = xn[M];
        float* drow = D + M * NODES;
        float v1 = 3.4e38f, v2 = 3.4e38f;
        int   c1 = 1 << 30,  c2 = 1 << 30;
#pragma unroll
        for (int fn = 0; fn < 4; ++fn) {
            f32x4 a = acc[fn][fm];
            float4 d;
            d.x = fmaxf(xv + ynv[fn].x - 2.0f * a[0], 0.0f);
            d.y = fmaxf(xv + ynv[fn].y - 2.0f * a[1], 0.0f);
            d.z = fmaxf(xv + ynv[fn].z - 2.0f * a[2], 0.0f);
            d.w = fmaxf(xv + ynv[fn].w - 2.0f * a[3], 0.0f);
            nt_store4(drow + n0 + fn * 16, d);
            float dv[4] = {d.x, d.y, d.z, d.w};
#pragma unroll
            for (int j = 0; j < 4; ++j) {
                int c = n0 + fn * 16 + j;
                if (dv[j] < v1 || (dv[j] == v1 && c < c1)) { v2 = v1; c2 = c1; v1 = dv[j]; c1 = c; }
                else if (dv[j] < v2 || (dv[j] == v2 && c < c2)) { v2 = dv[j]; c2 = c; }
            }
        }
        // merge across the 4 fk lanes (same frow): xor offsets 16, 32
#pragma unroll
        for (int off = 16; off < 64; off <<= 1) {
            float w1 = __shfl_xor(v1, off); int d1 = __shfl_xor(c1, off);
            float w2 = __shfl_xor(v2, off); int d2 = __shfl_xor(c2, off);
            if (w1 < v1 || (w1 == v1 && d1 < c1)) { v2 = v1; c2 = c1; v1 = w1; c1 = d1; }
            else if (w1 < v2 || (w1 == v2 && d1 < c2)) { v2 = w1; c2 = d1; }
            if (w2 < v2 || (w2 == v2 && d2 < c2)) {
                if (w2 < v1 || (w2 == v1 && d2 < c1)) { v2 = v1; c2 = c1; v1 = w2; c1 = d2; }
                else { v2 = w2; c2 = d2; }
            }
        }
        if (fk == 0) red[mloc * 2 + wc] = make_float4(v1, (float)c1, v2, (float)c2);
    }
    __syncthreads();
    if (tid < 128) {
        float4 a = red[tid * 2 + 0];
        float4 b = red[tid * 2 + 1];
        float v1 = a.x, c1 = a.y, v2 = a.z, c2 = a.w;
        if (b.x < v1 || (b.x == v1 && b.y < c1)) { v2 = v1; c2 = c1; v1 = b.x; c1 = b.y; }
        else if (b.x < v2 || (b.x == v2 && b.y < c2)) { v2 = b.x; c2 = b.y; }
        if (b.z < v2 || (b.z == v2 && b.w < c2)) {
            if (b.z < v1 || (b.z == v1 && b.w < c1)) { v2 = v1; c2 = c1; v1 = b.z; c1 = b.w; }
            else { v2 = b.z; c2 = b.w; }
        }
        partials[(size_t)(bm * 128 + tid) * 8 + bn] = make_float4(v1, c1, v2, c2);
    }
}

// ---------------- merge 8 block top-2s -> k, list ambiguous rows ----------------
__global__ __launch_bounds__(256) void finish1_k(const float4* __restrict__ partials,
                                                 float* __restrict__ out_k,
                                                 int* __restrict__ refine_cnt,
                                                 int* __restrict__ refine_list) {
    int r = blockIdx.x * 256 + threadIdx.x;
    float v1 = 3.4e38f, c1 = 2.0e9f, v2 = 3.4e38f, c2 = 2.0e9f;
#pragma unroll
    for (int i = 0; i < 8; ++i) {
        float4 p = partials[(size_t)r * 8 + i];
        if (p.x < v1 || (p.x == v1 && p.y < c1)) { v2 = v1; c2 = c1; v1 = p.x; c1 = p.y; }
        else if (p.x < v2 || (p.x == v2 && p.y < c2)) { v2 = p.x; c2 = p.y; }
        if (p.z < v2 || (p.z == v2 && p.w < c2)) {
            if (p.z < v1 || (p.z == v1 && p.w < c1)) { v2 = v1; c2 = c1; v1 = p.z; c1 = p.w; }
            else { v2 = p.z; c2 = p.w; }
        }
    }
    out_k[r] = c1;
    if (v2 - v1 < EPSGAP) {
        int slot = atomicAdd(refine_cnt, 1);
        refine_list[slot] = r;
    }
}

// ---------------- exact f32 re-argmin for near-tie rows (8-row batches) ----------------
__global__ __launch_bounds__(256) void refine_k(const float* __restrict__ ze,
                                                const float* __restrict__ cb,
                                                const float* __restrict__ xn,
                                                const float* __restrict__ yn,
                                                const int* __restrict__ refine_cnt,
                                                const int* __restrict__ refine_list,
                                                float* __restrict__ out_k) {
    __shared__ float zs[RB][ZD];
    __shared__ float rvs[RB][4];
    __shared__ int   rcs[RB][4];
    const int n   = *refine_cnt;
    const int tid = threadIdx.x;
    const int lane = tid & 63, w = tid >> 6;

    for (int base = blockIdx.x * RB; base < n; base += gridDim.x * RB) {
        int nb = n - base; if (nb > RB) nb = RB;
        __syncthreads();
        {
            int rr = tid >> 5, p = tid & 31;
            if (rr < nb) {
                int r = refine_list[base + rr];
                const float4* zp = (const float4*)(ze + (size_t)r * ZD);
                ((float4*)zs[rr])[p]      = zp[p];
                ((float4*)zs[rr])[p + 32] = zp[p + 32];
            }
        }
        __syncthreads();

        float dot[RB][4];
#pragma unroll
        for (int rr = 0; rr < RB; ++rr)
#pragma unroll
            for (int m = 0; m < 4; ++m) dot[rr][m] = 0.0f;

        for (int k4 = 0; k4 < 64; ++k4) {
            float4 c[4];
#pragma unroll
            for (int m = 0; m < 4; ++m)
                c[m] = *(const float4*)(cb + (size_t)(tid + m * 256) * ZD + k4 * 4);
#pragma unroll
            for (int rr = 0; rr < RB; ++rr) {
                float4 zv = ((const float4*)zs[rr])[k4];
#pragma unroll
                for (int m = 0; m < 4; ++m) {
                    float d = dot[rr][m];
                    d = fmaf(zv.x, c[m].x, d);
                    d = fmaf(zv.y, c[m].y, d);
                    d = fmaf(zv.z, c[m].z, d);
                    d = fmaf(zv.w, c[m].w, d);
                    dot[rr][m] = d;
                }
            }
        }

        float ynv[4];
#pragma unroll
        for (int m = 0; m < 4; ++m) ynv[m] = yn[tid + m * 256];

        for (int rr = 0; rr < nb; ++rr) {
            int r = refine_list[base + rr];
            float xv = xn[r];
            float bv = 3.4e38f; int bc = 1 << 30;
#pragma unroll
            for (int m = 0; m < 4; ++m) {
                int j = tid + m * 256;
                float d = fmaxf((xv + ynv[m]) - 2.0f * dot[rr][m], 0.0f);
                if (d < bv) { bv = d; bc = j; }
            }
#pragma unroll
            for (int off = 32; off; off >>= 1) {
                float ov = __shfl_down(bv, off);
                int   oc = __shfl_down(bc, off);
                if (ov < bv || (ov == bv && oc < bc)) { bv = ov; bc = oc; }
            }
            if (lane == 0) { rvs[rr][w] = bv; rcs[rr][w] = bc; }
        }
        __syncthreads();
        if (tid < nb) {
            float fv = rvs[tid][0]; int fc = rcs[tid][0];
#pragma unroll
            for (int i = 1; i < 4; ++i)
                if (rvs[tid][i] < fv || (rvs[tid][i] == fv && rcs[tid][i] < fc)) { fv = rvs[tid][i]; fc = rcs[tid][i]; }
            out_k[refine_list[base + tid]] = (float)fc;
        }
    }
}

// ---------------- z_q gather + neighbour weights (separable Gaussian, nt stores) ----------------
__global__ __launch_bounds__(256) void finish2_k(const float* __restrict__ cb,
                                                 const int* __restrict__ epoch_p,
                                                 const float* __restrict__ kf,
                                                 float* __restrict__ out_zq,
                                                 float* __restrict__ out_nw) {
    __shared__ float g[32];   // g[t] = exp(-t^2/(2 sig^2)); w = g[|dx|]*g[|dy|]

    int ep = epoch_p[0];
    double sig = 16.0 * exp((double)ep * -0.034657359027997265);
    float ninv = (float)(-1.0 / (2.0 * sig * sig));
    if (threadIdx.x < 32) {
        float t = (float)threadIdx.x;
        g[threadIdx.x] = __expf(t * t * ninv);
    }
    __syncthreads();

    int row  = blockIdx.x * 4 + (threadIdx.x >> 6);
    int lane = threadIdx.x & 63;
    int k = (int)kf[row];

    nt_store4(out_zq + (size_t)row * ZD + lane * 4,
              ((const float4*)(cb + (size_t)k * ZD))[lane]);

    int kx = k >> 5, ky = k & 31;
    float* nwp = out_nw + (size_t)row * NODES;
#pragma unroll
    for (int i = 0; i < 4; ++i) {
        int q = i * 64 + lane;
        int n = q * 4;
        int nx = n >> 5;
        int ny = n & 31;
        float gx = g[abs(nx - ky)];
        float4 w;
        w.x = gx * g[abs(ny + 0 - kx)];
        w.y = gx * g[abs(ny + 1 - kx)];
        w.z = gx * g[abs(ny + 2 - kx)];
        w.w = gx * g[abs(ny + 3 - kx)];
        nt_store4(nwp + q * 4, w);
    }
}

extern "C" void kernel_launch(void* const* d_in, const int* in_sizes, int n_in,
                              void* d_out, int out_size, void* d_ws, size_t ws_size,
                              hipStream_t stream) {
    const float* z_e      = (const float*)d_in[0];
    const float* codebook = (const float*)d_in[1];
    const int*   epoch_p  = (const int*)d_in[2];
    float* out = (float*)d_out;

    // scratch in d_out regions overwritten later (stream-ordered):
    //  nw region (268MB): Ap, Bp, xn, yn, partials  (finish2 writes nw last)
    //  z_q region: refine count + list              (finish2 writes z_q last)
    char* scratch = (char*)(out + OFF_NW);
    ushort* Ap = (ushort*)scratch;                          // 67,108,864 B
    ushort* Bp = (ushort*)(scratch + 67108864);             //  1,572,864 B
    float*  xn = (float*) (scratch + 68681728);             //    262,144 B
    float*  yn = (float*) (scratch + 68943872);             //      4,096 B
    float4* partials = (float4*)(scratch + 68947968);       //  8,388,608 B
    int* refine_cnt  = (int*)(out + OFF_ZQ);
    int* refine_list = refine_cnt + 1;

    split_k<<<BATCH / 4, 256, 0, stream>>>(z_e, Ap, xn, out + OFF_ZE, nullptr, 1);
    split_k<<<NODES / 4, 256, 0, stream>>>(codebook, Bp, yn, nullptr, refine_cnt, 0);

    dist_mfma_k<<<4096, 256, 0, stream>>>(Ap, Bp, xn, yn, out + OFF_DIST, partials);

    finish1_k<<<BATCH / 256, 256, 0, stream>>>(partials, out + OFF_K, refine_cnt, refine_list);
    refine_k<<<512, 256, 0, stream>>>(z_e, codebook, xn, yn, refine_cnt, refine_list, out + OFF_K);
    finish2_k<<<BATCH / 4, 256, 0, stream>>>(codebook, epoch_p, out + OFF_K,
                                             out + OFF_ZQ, out + OFF_NW);
}